// Round 23
// baseline (109.567 us; speedup 1.0000x reference)
//
#include <hip/hip_runtime.h>
#include <math.h>

#define NIN 91392        // 17*21*16*16
#define DIN 8
#define DOUT 16
#define NCHUNK (NIN / 8) // 11424 chunks of 8 n
#define GRID_P 768       // 3 blocks/CU co-resident (48 KB LDS)
#define TPB 512          // 8 waves

typedef float f32x4 __attribute__((ext_vector_type(4)));

// async global->LDS width16: dest = lane-uniform base + lane*16; src per-lane
#define GLD_LDS16(gp, lp) __builtin_amdgcn_global_load_lds(                    \
    (const __attribute__((address_space(1))) float*)(gp),                      \
    (__attribute__((address_space(3))) float*)(lp), 16, 0, 0)

// inline-asm LDS read (R17-verified): no memory clobber -> compiler can't
// inject vmcnt(0) drains; ordering carried by explicit waits + barriers.
#define DSR128(dst, pf)                                                        \
    asm volatile("ds_read_b128 %0, %1" : "=v"(dst)                             \
        : "v"((unsigned)(__SIZE_TYPE__)                                        \
              (const __attribute__((address_space(3))) float*)(pf)))

// ---- round staging (R15/R17-verified addressing) ----
__device__ __forceinline__ void issue_round(
    const float* __restrict__ x, const float* __restrict__ W,
    float* lds, int bid, int grid, int k, int lane, int wave)
{
    const int wR_half = lane >> 5;
    const int wFlo = (lane & 31) * 4;
    const int xb = (wave & 3) * 4 + (lane >> 4);
    const int xu = (lane & 15) ^ (xb & 7);
    const int xs = wave >> 2;
    const int bufb = k & 1;
    {   const int m = 2*wave; const int s = m>>3, p = m&7;
        int c_ = bid + (2*k + s) * grid; if (c_ >= NCHUNK) c_ = bid;
        const int R = 2*p + wR_half;
        GLD_LDS16(W + (size_t)(R>>3)*((size_t)NIN*128)
                    + (size_t)(c_*8 + (R&7))*128 + wFlo,
                  lds + bufb*4096 + s*2048 + p*256);
    }
    {   const int m = 2*wave+1; const int s = m>>3, p = m&7;
        int c_ = bid + (2*k + s) * grid; if (c_ >= NCHUNK) c_ = bid;
        const int R = 2*p + wR_half;
        GLD_LDS16(W + (size_t)(R>>3)*((size_t)NIN*128)
                    + (size_t)(c_*8 + (R&7))*128 + wFlo,
                  lds + bufb*4096 + s*2048 + p*256);
    }
    {   int c_ = bid + (2*k + xs) * grid; if (c_ >= NCHUNK) c_ = bid;
        GLD_LDS16(x + (size_t)xb*((size_t)NIN*8) + (size_t)c_*64 + xu*4,
                  lds + 8192 + bufb*2048 + xs*1024 + (wave&3)*256);
    }
}

// squash slice helper: load the 16-float (b,j) group of sbuf, scale, squash,
// return this thread's og-slice of the resulting v. ~20 VALU, once per block.
__device__ __forceinline__ f32x4 squash_slice(
    const float* __restrict__ sbuf, int grpbase, int og, float scale)
{
    f32x4 a = scale * *(const f32x4*)(sbuf + grpbase + 0);
    f32x4 b = scale * *(const f32x4*)(sbuf + grpbase + 4);
    f32x4 c = scale * *(const f32x4*)(sbuf + grpbase + 8);
    f32x4 d = scale * *(const f32x4*)(sbuf + grpbase + 12);
    const float sn = a.x*a.x + a.y*a.y + a.z*a.z + a.w*a.w
                   + b.x*b.x + b.y*b.y + b.z*b.z + b.w*b.w
                   + c.x*c.x + c.y*c.y + c.z*c.z + c.w*c.w
                   + d.x*d.x + d.y*d.y + d.z*d.z + d.w*d.w;
    const float fac = sn / ((1.f + sn) * sqrtf(sn + 1e-7f));
    const f32x4 sel = (og == 0) ? a : (og == 1) ? b : (og == 2) ? c : d;
    return sel * fac;
}

// ---- R17/R22-verified pass kernel; vin computed inline from sbuf ----
// PASS 0: s0 partial = sum_n u (x0.5 applied when sbuf0 is consumed).
// PASS 1: vin = sgn*squash(0.5*sbuf0).   PASS 2: vin = sgn*(v0 + squash(sbuf1)).
template<int PASS>
__global__ __launch_bounds__(TPB) void caps_pass(
    const float* __restrict__ x, const float* __restrict__ W,
    const float* __restrict__ sb0, const float* __restrict__ sb1,
    float* __restrict__ part, int grid)
{
    const int t = threadIdx.x;
    const int lane = t & 63;
    const int wave = t >> 6;
    const int og = lane & 3;
    const int j  = (lane >> 2) & 1;
    const int b0 = lane >> 3;
    const int bid = blockIdx.x;

    __shared__ __align__(16) float lds[12288];

    const float sgn = j ? -1.f : 1.f;

    f32x4 vinA = {0.f,0.f,0.f,0.f}, vinB = {0.f,0.f,0.f,0.f};
    if (PASS == 1) {
        vinA = sgn * squash_slice(sb0, b0 * 32 + j * 16, og, 0.5f);
        vinB = sgn * squash_slice(sb0, (b0 + 8) * 32 + j * 16, og, 0.5f);
    } else if (PASS == 2) {
        vinA = sgn * (squash_slice(sb0, b0 * 32 + j * 16, og, 0.5f)
                    + squash_slice(sb1, b0 * 32 + j * 16, og, 1.f));
        vinB = sgn * (squash_slice(sb0, (b0 + 8) * 32 + j * 16, og, 0.5f)
                    + squash_slice(sb1, (b0 + 8) * 32 + j * 16, og, 1.f));
    }

    f32x4 accA = {0.f,0.f,0.f,0.f};
    f32x4 accB = {0.f,0.f,0.f,0.f};

    const int R_rounds = (NCHUNK + 2*grid - 1) / (2*grid);

    issue_round(x, W, lds, bid, grid, 0, lane, wave);
    issue_round(x, W, lds, bid, grid, 1, lane, wave);

    for (int k = 0; k < R_rounds; ++k) {
        asm volatile("s_waitcnt vmcnt(3)" ::: "memory");
        __builtin_amdgcn_s_barrier();

        const int bufb = k & 1;
        #pragma unroll
        for (int s = 0; s < 2; ++s) {
            const int c = bid + (2*k + s) * grid;
            if (c < NCHUNK) {
                const float* wrow = lds + bufb*4096 + s*2048
                                  + (j*8 + wave)*128 + og*4;
                const float* xrg  = lds + 8192 + bufb*2048 + s*1024;
                const int u0i = wave * 2;
                const int swz = (b0 & 7);

                f32x4 u0 = {0.f,0.f,0.f,0.f};
                f32x4 u1 = {0.f,0.f,0.f,0.f};
                {
                    f32x4 W0,W1,W2,W3,XA,XB;
                    DSR128(W0, wrow + 0);
                    DSR128(W1, wrow + 16);
                    DSR128(W2, wrow + 32);
                    DSR128(W3, wrow + 48);
                    DSR128(XA, xrg + b0*64     + ((u0i^swz) << 2));
                    DSR128(XB, xrg + (b0+8)*64 + ((u0i^swz) << 2));
                    asm volatile("s_waitcnt lgkmcnt(0)");
                    __builtin_amdgcn_sched_barrier(0);
                    u0 += W0*XA.x; u0 += W1*XA.y; u0 += W2*XA.z; u0 += W3*XA.w;
                    u1 += W0*XB.x; u1 += W1*XB.y; u1 += W2*XB.z; u1 += W3*XB.w;
                }
                {
                    f32x4 W4,W5,W6,W7,XC,XD;
                    DSR128(W4, wrow + 64);
                    DSR128(W5, wrow + 80);
                    DSR128(W6, wrow + 96);
                    DSR128(W7, wrow + 112);
                    DSR128(XC, xrg + b0*64     + (((u0i+1)^swz) << 2));
                    DSR128(XD, xrg + (b0+8)*64 + (((u0i+1)^swz) << 2));
                    asm volatile("s_waitcnt lgkmcnt(0)");
                    __builtin_amdgcn_sched_barrier(0);
                    u0 += W4*XC.x; u0 += W5*XC.y; u0 += W6*XC.z; u0 += W7*XC.w;
                    u1 += W4*XD.x; u1 += W5*XD.y; u1 += W6*XD.z; u1 += W7*XD.w;
                }

                if (PASS == 0) {
                    accA += u0;
                    accB += u1;
                } else {
                    float m0 = vinA.x*u0.x + vinA.y*u0.y + vinA.z*u0.z + vinA.w*u0.w;
                    float m1 = vinB.x*u1.x + vinB.y*u1.y + vinB.z*u1.z + vinB.w*u1.w;
                    m0 += __shfl_xor(m0, 1);  m1 += __shfl_xor(m1, 1);
                    m0 += __shfl_xor(m0, 2);  m1 += __shfl_xor(m1, 2);
                    m0 += __shfl_xor(m0, 4);  m1 += __shfl_xor(m1, 4);
                    const float cA = __builtin_amdgcn_rcpf(1.f + __expf(-sgn * m0));
                    const float cB = __builtin_amdgcn_rcpf(1.f + __expf(-sgn * m1));
                    accA += u0 * cA;
                    accB += u1 * cB;
                }
            }
        }
        asm volatile("s_waitcnt lgkmcnt(0)" ::: "memory");
        __builtin_amdgcn_s_barrier();
        issue_round(x, W, lds, bid, grid, k + 2, lane, wave);
    }

    asm volatile("s_waitcnt vmcnt(0)" ::: "memory");
    __syncthreads();

    // ---- epilogue: cross-wave reduce; column-major part[col*grid + bid] ----
    {
        float* sl = lds + wave * 576 + lane * 9;
        sl[0]=accA.x; sl[1]=accA.y; sl[2]=accA.z; sl[3]=accA.w;
        sl[4]=accB.x; sl[5]=accB.y; sl[6]=accB.z; sl[7]=accB.w;
    }
    __syncthreads();
    if (t < 64) {
        float s[8];
        #pragma unroll
        for (int q = 0; q < 8; ++q) s[q] = 0.f;
        #pragma unroll
        for (int w = 0; w < 8; ++w) {
            const float* p = lds + w * 576 + t * 9;
            #pragma unroll
            for (int q = 0; q < 8; ++q) s[q] += p[q];
        }
        const int tb0 = t >> 3, tj = (t >> 2) & 1, tog = t & 3;
        #pragma unroll
        for (int q = 0; q < 4; ++q) {
            part[(size_t)(tb0*32 + tj*16 + tog*4 + q) * grid + bid] = s[q];
            part[(size_t)((tb0+8)*32 + tj*16 + tog*4 + q) * grid + bid] = s[4+q];
        }
    }
}

// ---- column reduce: 512 blocks (one per output col), 256 threads ----
__global__ __launch_bounds__(256) void caps_colred(
    const float* __restrict__ part, float* __restrict__ sbuf, int grid)
{
    const int col = blockIdx.x;
    const int t = threadIdx.x;
    const float* p = part + (size_t)col * grid;
    float s = 0.f;
    for (int g = t; g < grid; g += 256) s += p[g];
    __shared__ float red[256];
    red[t] = s;
    __syncthreads();
    #pragma unroll
    for (int ofs = 128; ofs >= 64; ofs >>= 1) {
        if (t < ofs) red[t] += red[t + ofs];
        __syncthreads();
    }
    if (t < 64) {
        float v = red[t];
        v += __shfl_xor(v, 1);  v += __shfl_xor(v, 2);
        v += __shfl_xor(v, 4);  v += __shfl_xor(v, 8);
        v += __shfl_xor(v, 16); v += __shfl_xor(v, 32);
        if (t == 0) sbuf[col] = v;
    }
}

// ---- final squash: 1 block, 512 threads -> out ----
__global__ __launch_bounds__(512) void caps_squash_out(
    const float* __restrict__ sbuf, float* __restrict__ vout)
{
    const int t = threadIdx.x;        // col = b*32 + j*16 + o
    float sv = sbuf[t];
    float sq = sv * sv;               // |s|^2 over the 16 o-lanes of the group
    sq += __shfl_xor(sq, 1);
    sq += __shfl_xor(sq, 2);
    sq += __shfl_xor(sq, 4);
    sq += __shfl_xor(sq, 8);
    const float sn = sq;
    vout[t] = sv * sn / ((1.f + sn) * sqrtf(sn + 1e-7f));
}

extern "C" void kernel_launch(void* const* d_in, const int* in_sizes, int n_in,
                              void* d_out, int out_size, void* d_ws, size_t ws_size,
                              hipStream_t stream) {
    const float* x = (const float*)d_in[0];
    const float* W = (const float*)d_in[1];
    float* out = (float*)d_out;

    // grid clamped to workspace (part = 512*GRID floats + 3 sbufs)
    size_t maxg = (ws_size - 12288) / (512 * sizeof(float));
    int GRID = (int)(maxg < GRID_P ? maxg : GRID_P);
    if (GRID < 1) GRID = 1;

    float* part  = (float*)d_ws;               // 512*GRID floats (1.5 MB)
    float* sbuf0 = part + (size_t)512 * GRID;  // 512
    float* sbuf1 = sbuf0 + 512;                // 512
    float* sbuf2 = sbuf1 + 512;                // 512

    caps_pass<0><<<GRID, TPB, 0, stream>>>(x, W, nullptr, nullptr, part, GRID);
    caps_colred<<<512, 256, 0, stream>>>(part, sbuf0, GRID);
    caps_pass<1><<<GRID, TPB, 0, stream>>>(x, W, sbuf0, nullptr, part, GRID);
    caps_colred<<<512, 256, 0, stream>>>(part, sbuf1, GRID);
    caps_pass<2><<<GRID, TPB, 0, stream>>>(x, W, sbuf0, sbuf1, part, GRID);
    caps_colred<<<512, 256, 0, stream>>>(part, sbuf2, GRID);
    caps_squash_out<<<1, 512, 0, stream>>>(sbuf2, out);
}

// Round 24
// 104.613 us; speedup vs baseline: 1.0474x; 1.0474x over previous
//
#include <hip/hip_runtime.h>
#include <math.h>

#define NIN 91392        // 17*21*16*16
#define DIN 8
#define DOUT 16
#define NCHUNK (NIN / 8) // 11424 chunks of 8 n
#define GRID_P 768       // 3 blocks/CU co-resident (48.25 KB LDS)
#define TPB 512          // 8 waves

typedef float f32x4 __attribute__((ext_vector_type(4)));

// async global->LDS width16: dest = lane-uniform base + lane*16; src per-lane
#define GLD_LDS16(gp, lp) __builtin_amdgcn_global_load_lds(                    \
    (const __attribute__((address_space(1))) float*)(gp),                      \
    (__attribute__((address_space(3))) float*)(lp), 16, 0, 0)

// inline-asm LDS read (R17-verified): no memory clobber -> compiler can't
// inject vmcnt(0) drains; ordering carried by explicit waits + barriers.
#define DSR128(dst, pf)                                                        \
    asm volatile("ds_read_b128 %0, %1" : "=v"(dst)                             \
        : "v"((unsigned)(__SIZE_TYPE__)                                        \
              (const __attribute__((address_space(3))) float*)(pf)))

// W-chunk layout (R24 conflict fix): rows r=j*8+nn; j=1 half padded +64B so
// the W ds_read's j=0 lanes (banks {0-15}+16(i&1)) and j=1 lanes (now +16
// banks) cover all 32 banks -> kills the measured 2.92M 2-way conflicts.
// Region strides: chunk 2064 floats, dbuf 4128; x region at 8256.

// ---- round staging (R15/R17 addressing + j-half pad) ----
__device__ __forceinline__ void issue_round(
    const float* __restrict__ x, const float* __restrict__ W,
    float* lds, int bid, int grid, int k, int lane, int wave)
{
    const int wR_half = lane >> 5;
    const int wFlo = (lane & 31) * 4;
    const int xb = (wave & 3) * 4 + (lane >> 4);
    const int xu = (lane & 15) ^ (xb & 7);
    const int xs = wave >> 2;
    const int bufb = k & 1;
    {   const int m = 2*wave; const int s = m>>3, p = m&7;
        int c_ = bid + (2*k + s) * grid; if (c_ >= NCHUNK) c_ = bid;
        const int R = 2*p + wR_half;
        GLD_LDS16(W + (size_t)(R>>3)*((size_t)NIN*128)
                    + (size_t)(c_*8 + (R&7))*128 + wFlo,
                  lds + bufb*4128 + s*2064 + p*256 + (p&4)*4);
    }
    {   const int m = 2*wave+1; const int s = m>>3, p = m&7;
        int c_ = bid + (2*k + s) * grid; if (c_ >= NCHUNK) c_ = bid;
        const int R = 2*p + wR_half;
        GLD_LDS16(W + (size_t)(R>>3)*((size_t)NIN*128)
                    + (size_t)(c_*8 + (R&7))*128 + wFlo,
                  lds + bufb*4128 + s*2064 + p*256 + (p&4)*4);
    }
    {   int c_ = bid + (2*k + xs) * grid; if (c_ >= NCHUNK) c_ = bid;
        GLD_LDS16(x + (size_t)xb*((size_t)NIN*8) + (size_t)c_*64 + xu*4,
                  lds + 8256 + bufb*2048 + xs*1024 + (wave&3)*256);
    }
}

// squash slice helper: load the 16-float (b,j) group of sbuf, scale, squash,
// return this thread's og-slice of the resulting v.
__device__ __forceinline__ f32x4 squash_slice(
    const float* __restrict__ sbuf, int grpbase, int og, float scale)
{
    f32x4 a = scale * *(const f32x4*)(sbuf + grpbase + 0);
    f32x4 b = scale * *(const f32x4*)(sbuf + grpbase + 4);
    f32x4 c = scale * *(const f32x4*)(sbuf + grpbase + 8);
    f32x4 d = scale * *(const f32x4*)(sbuf + grpbase + 12);
    const float sn = a.x*a.x + a.y*a.y + a.z*a.z + a.w*a.w
                   + b.x*b.x + b.y*b.y + b.z*b.z + b.w*b.w
                   + c.x*c.x + c.y*c.y + c.z*c.z + c.w*c.w
                   + d.x*d.x + d.y*d.y + d.z*d.z + d.w*d.w;
    const float fac = sn / ((1.f + sn) * sqrtf(sn + 1e-7f));
    const f32x4 sel = (og == 0) ? a : (og == 1) ? b : (og == 2) ? c : d;
    return sel * fac;
}

// ---- pass kernel (R23 logic, padded-W addressing) ----
// PASS 0: s0 partial = sum_n u (x0.5 applied when sbuf0 is consumed).
// PASS 1: vin = sgn*squash(0.5*sbuf0).  PASS 2: vin = sgn*(v0 + squash(sbuf1)).
template<int PASS>
__global__ __launch_bounds__(TPB) void caps_pass(
    const float* __restrict__ x, const float* __restrict__ W,
    const float* __restrict__ sb0, const float* __restrict__ sb1,
    float* __restrict__ part, int grid)
{
    const int t = threadIdx.x;
    const int lane = t & 63;
    const int wave = t >> 6;
    const int og = lane & 3;
    const int j  = (lane >> 2) & 1;
    const int b0 = lane >> 3;
    const int bid = blockIdx.x;

    __shared__ __align__(16) float lds[12352];   // W dbuf 8256 + x dbuf 4096

    const float sgn = j ? -1.f : 1.f;

    f32x4 vinA = {0.f,0.f,0.f,0.f}, vinB = {0.f,0.f,0.f,0.f};
    if (PASS == 1) {
        vinA = sgn * squash_slice(sb0, b0 * 32 + j * 16, og, 0.5f);
        vinB = sgn * squash_slice(sb0, (b0 + 8) * 32 + j * 16, og, 0.5f);
    } else if (PASS == 2) {
        vinA = sgn * (squash_slice(sb0, b0 * 32 + j * 16, og, 0.5f)
                    + squash_slice(sb1, b0 * 32 + j * 16, og, 1.f));
        vinB = sgn * (squash_slice(sb0, (b0 + 8) * 32 + j * 16, og, 0.5f)
                    + squash_slice(sb1, (b0 + 8) * 32 + j * 16, og, 1.f));
    }

    f32x4 accA = {0.f,0.f,0.f,0.f};
    f32x4 accB = {0.f,0.f,0.f,0.f};

    const int R_rounds = (NCHUNK + 2*grid - 1) / (2*grid);

    issue_round(x, W, lds, bid, grid, 0, lane, wave);
    issue_round(x, W, lds, bid, grid, 1, lane, wave);

    for (int k = 0; k < R_rounds; ++k) {
        asm volatile("s_waitcnt vmcnt(3)" ::: "memory");
        __builtin_amdgcn_s_barrier();

        const int bufb = k & 1;
        #pragma unroll
        for (int s = 0; s < 2; ++s) {
            const int c = bid + (2*k + s) * grid;
            if (c < NCHUNK) {
                const float* wrow = lds + bufb*4128 + s*2064
                                  + (j*8 + wave)*128 + j*16 + og*4;
                const float* xrg  = lds + 8256 + bufb*2048 + s*1024;
                const int u0i = wave * 2;
                const int swz = (b0 & 7);

                f32x4 u0 = {0.f,0.f,0.f,0.f};
                f32x4 u1 = {0.f,0.f,0.f,0.f};
                {
                    f32x4 W0,W1,W2,W3,XA,XB;
                    DSR128(W0, wrow + 0);
                    DSR128(W1, wrow + 16);
                    DSR128(W2, wrow + 32);
                    DSR128(W3, wrow + 48);
                    DSR128(XA, xrg + b0*64     + ((u0i^swz) << 2));
                    DSR128(XB, xrg + (b0+8)*64 + ((u0i^swz) << 2));
                    asm volatile("s_waitcnt lgkmcnt(0)");
                    __builtin_amdgcn_sched_barrier(0);
                    u0 += W0*XA.x; u0 += W1*XA.y; u0 += W2*XA.z; u0 += W3*XA.w;
                    u1 += W0*XB.x; u1 += W1*XB.y; u1 += W2*XB.z; u1 += W3*XB.w;
                }
                {
                    f32x4 W4,W5,W6,W7,XC,XD;
                    DSR128(W4, wrow + 64);
                    DSR128(W5, wrow + 80);
                    DSR128(W6, wrow + 96);
                    DSR128(W7, wrow + 112);
                    DSR128(XC, xrg + b0*64     + (((u0i+1)^swz) << 2));
                    DSR128(XD, xrg + (b0+8)*64 + (((u0i+1)^swz) << 2));
                    asm volatile("s_waitcnt lgkmcnt(0)");
                    __builtin_amdgcn_sched_barrier(0);
                    u0 += W4*XC.x; u0 += W5*XC.y; u0 += W6*XC.z; u0 += W7*XC.w;
                    u1 += W4*XD.x; u1 += W5*XD.y; u1 += W6*XD.z; u1 += W7*XD.w;
                }

                if (PASS == 0) {
                    accA += u0;
                    accB += u1;
                } else {
                    float m0 = vinA.x*u0.x + vinA.y*u0.y + vinA.z*u0.z + vinA.w*u0.w;
                    float m1 = vinB.x*u1.x + vinB.y*u1.y + vinB.z*u1.z + vinB.w*u1.w;
                    m0 += __shfl_xor(m0, 1);  m1 += __shfl_xor(m1, 1);
                    m0 += __shfl_xor(m0, 2);  m1 += __shfl_xor(m1, 2);
                    m0 += __shfl_xor(m0, 4);  m1 += __shfl_xor(m1, 4);
                    const float cA = __builtin_amdgcn_rcpf(1.f + __expf(-sgn * m0));
                    const float cB = __builtin_amdgcn_rcpf(1.f + __expf(-sgn * m1));
                    accA += u0 * cA;
                    accB += u1 * cB;
                }
            }
        }
        asm volatile("s_waitcnt lgkmcnt(0)" ::: "memory");
        __builtin_amdgcn_s_barrier();
        issue_round(x, W, lds, bid, grid, k + 2, lane, wave);
    }

    asm volatile("s_waitcnt vmcnt(0)" ::: "memory");
    __syncthreads();

    // ---- epilogue: cross-wave reduce; column-major part[col*grid + bid] ----
    {
        float* sl = lds + wave * 576 + lane * 9;
        sl[0]=accA.x; sl[1]=accA.y; sl[2]=accA.z; sl[3]=accA.w;
        sl[4]=accB.x; sl[5]=accB.y; sl[6]=accB.z; sl[7]=accB.w;
    }
    __syncthreads();
    if (t < 64) {
        float s[8];
        #pragma unroll
        for (int q = 0; q < 8; ++q) s[q] = 0.f;
        #pragma unroll
        for (int w = 0; w < 8; ++w) {
            const float* p = lds + w * 576 + t * 9;
            #pragma unroll
            for (int q = 0; q < 8; ++q) s[q] += p[q];
        }
        const int tb0 = t >> 3, tj = (t >> 2) & 1, tog = t & 3;
        #pragma unroll
        for (int q = 0; q < 4; ++q) {
            part[(size_t)(tb0*32 + tj*16 + tog*4 + q) * grid + bid] = s[q];
            part[(size_t)((tb0+8)*32 + tj*16 + tog*4 + q) * grid + bid] = s[4+q];
        }
    }
}

// ---- column reduce: 512 blocks (one per output col), 256 threads ----
__global__ __launch_bounds__(256) void caps_colred(
    const float* __restrict__ part, float* __restrict__ sbuf, int grid)
{
    const int col = blockIdx.x;
    const int t = threadIdx.x;
    const float* p = part + (size_t)col * grid;
    float s = 0.f;
    for (int g = t; g < grid; g += 256) s += p[g];
    __shared__ float red[256];
    red[t] = s;
    __syncthreads();
    #pragma unroll
    for (int ofs = 128; ofs >= 64; ofs >>= 1) {
        if (t < ofs) red[t] += red[t + ofs];
        __syncthreads();
    }
    if (t < 64) {
        float v = red[t];
        v += __shfl_xor(v, 1);  v += __shfl_xor(v, 2);
        v += __shfl_xor(v, 4);  v += __shfl_xor(v, 8);
        v += __shfl_xor(v, 16); v += __shfl_xor(v, 32);
        if (t == 0) sbuf[col] = v;
    }
}

// ---- final squash: 1 block, 512 threads -> out ----
__global__ __launch_bounds__(512) void caps_squash_out(
    const float* __restrict__ sbuf, float* __restrict__ vout)
{
    const int t = threadIdx.x;        // col = b*32 + j*16 + o
    float sv = sbuf[t];
    float sq = sv * sv;               // |s|^2 over the 16 o-lanes of the group
    sq += __shfl_xor(sq, 1);
    sq += __shfl_xor(sq, 2);
    sq += __shfl_xor(sq, 4);
    sq += __shfl_xor(sq, 8);
    const float sn = sq;
    vout[t] = sv * sn / ((1.f + sn) * sqrtf(sn + 1e-7f));
}

extern "C" void kernel_launch(void* const* d_in, const int* in_sizes, int n_in,
                              void* d_out, int out_size, void* d_ws, size_t ws_size,
                              hipStream_t stream) {
    const float* x = (const float*)d_in[0];
    const float* W = (const float*)d_in[1];
    float* out = (float*)d_out;

    // grid clamped to workspace (part = 512*GRID floats + 3 sbufs)
    size_t maxg = (ws_size - 12288) / (512 * sizeof(float));
    int GRID = (int)(maxg < GRID_P ? maxg : GRID_P);
    if (GRID < 1) GRID = 1;

    float* part  = (float*)d_ws;               // 512*GRID floats (1.5 MB)
    float* sbuf0 = part + (size_t)512 * GRID;  // 512
    float* sbuf1 = sbuf0 + 512;                // 512
    float* sbuf2 = sbuf1 + 512;                // 512

    caps_pass<0><<<GRID, TPB, 0, stream>>>(x, W, nullptr, nullptr, part, GRID);
    caps_colred<<<512, 256, 0, stream>>>(part, sbuf0, GRID);
    caps_pass<1><<<GRID, TPB, 0, stream>>>(x, W, sbuf0, nullptr, part, GRID);
    caps_colred<<<512, 256, 0, stream>>>(part, sbuf1, GRID);
    caps_pass<2><<<GRID, TPB, 0, stream>>>(x, W, sbuf0, sbuf1, part, GRID);
    caps_colred<<<512, 256, 0, stream>>>(part, sbuf2, GRID);
    caps_squash_out<<<1, 512, 0, stream>>>(sbuf2, out);
}